// Round 10
// baseline (2017.714 us; speedup 1.0000x reference)
//
#include <hip/hip_runtime.h>

// DFPS: density-weighted Manhattan furthest point sampling.
// points:   [B, N, 3] f32   (B=4, N=8192 fixed by the problem)
// features: [B, C, N] f32   (unused)
// npoint:   int scalar (device, d_in[2])
// out:      [B, npoint] int32 indices
//
// FPS structure (R9 = R8's cheap f32 loop + R3's single barrier):
//  - distance loop: nv = fmin(v, d*pw), f32 chain max (8 VALU/pt)
//  - post-loop: descending select-scan -> smallest k with v[k]==tb
//  - ONE u64 key per thread = (bits(tb)<<32) | (N-1-idx)  (min-idx ties)
//  - DPP u64 wave max -> lane63 ds_max_u64 -> single barrier -> index
//  v[] is bit-exact vs ref's min(md,d)*pw (x->rnd(x*pw) monotone, min
//  commutes; proven R8). Key/tie machinery proven R3-R7.

#define NPTS 8192
#define DENS_BLOCK 256
#define DENS_SPLIT 4
#define FPS_THREADS 512
#define FPS_P 16   // FPS_THREADS * FPS_P == NPTS

typedef float v2f __attribute__((ext_vector_type(2)));

// ---------------- density ----------------
// j-coords are wave-uniform -> scalar loads, no LDS, no barriers.

__global__ void dfps_density_partial(const float* __restrict__ pts,
                                     unsigned short* __restrict__ pen4, int N) {
#pragma clang fp contract(off)
    const float R2 = (float)(0.4 * 0.4);  // matches JAX scalar promotion
    const int b = blockIdx.y;
    const int z = blockIdx.z;
    const int i = blockIdx.x * blockDim.x + threadIdx.x;
    const float* P = pts + (size_t)b * N * 3;

    const v2f px2 = {P[i * 3 + 0], P[i * 3 + 0]};
    const v2f py2 = {P[i * 3 + 1], P[i * 3 + 1]};
    const v2f pz2 = {P[i * 3 + 2], P[i * 3 + 2]};

    const int j0 = z * (N / DENS_SPLIT);
    const int j1 = j0 + (N / DENS_SPLIT);

    int cnt = 0;
#pragma unroll 4
    for (int j = j0; j < j1; j += 2) {
        v2f qx = {P[3 * j + 0], P[3 * j + 3]};
        v2f qy = {P[3 * j + 1], P[3 * j + 4]};
        v2f qz = {P[3 * j + 2], P[3 * j + 5]};
        v2f dx = px2 - qx;
        v2f dy = py2 - qy;
        v2f dz = pz2 - qz;
        v2f d2 = dx * dx;       // contract(off): numpy mul-then-add rounding
        d2 = d2 + dy * dy;
        d2 = d2 + dz * dz;
        cnt += (d2.x <= R2) ? 1 : 0;
        cnt += (d2.y <= R2) ? 1 : 0;
    }
    pen4[(size_t)(z * 4 + b) * N + i] = (unsigned short)cnt;  // cnt <= 8192
}

// ---------------- FPS ----------------

// u64 max across the 64-lane wave via DPP; result valid in lane 63.
#define DPP_STEP(ctrl, rmask)                                                   \
    {                                                                           \
        unsigned int nlo = (unsigned int)__builtin_amdgcn_update_dpp(           \
            0, (int)klo, (ctrl), (rmask), 0xF, false);                          \
        unsigned int nhi = (unsigned int)__builtin_amdgcn_update_dpp(           \
            0, (int)khi, (ctrl), (rmask), 0xF, false);                          \
        unsigned long long o = ((unsigned long long)nhi << 32) | nlo;           \
        unsigned long long c = ((unsigned long long)khi << 32) | klo;           \
        if (o > c) { klo = nlo; khi = nhi; }                                    \
    }

__global__ void __launch_bounds__(FPS_THREADS, 1)
dfps_fps_kernel(const float* __restrict__ pts,
                const unsigned short* __restrict__ pen4,
                const int* __restrict__ npoint_p,
                int* __restrict__ out, int N) {
#pragma clang fp contract(off)
    const int b = blockIdx.x;
    const int tid = threadIdx.x;
    const int lane = tid & 63;
    const int npoint = *npoint_p;
    const float* Pb = pts + (size_t)b * N * 3;
    const int base = tid * FPS_P;
    const unsigned int L0 = (unsigned int)(N - 1 - base);  // key lo = L0 - k

    // Coordinate table in LDS (float4) -> one b128 winner fetch.
    __shared__ float4 tab[NPTS];                 // 128 KiB
    // Triple-buffered block-winner slot (ds_max_u64); every conflicting
    // access pair is separated by at least one __syncthreads() (see R3).
    __shared__ unsigned long long slot[3];

    // Per-thread state: coords, penalty, v[k] = running min of rnd(d*pw).
    float x[FPS_P], y[FPS_P], z[FPS_P], pw[FPS_P], v[FPS_P];
#pragma unroll
    for (int k = 0; k < FPS_P; ++k) {
        int idx = base + k;
        x[k] = Pb[idx * 3 + 0];
        y[k] = Pb[idx * 3 + 1];
        z[k] = Pb[idx * 3 + 2];
        int c01 = (int)pen4[(size_t)(0 * 4 + b) * N + idx] +
                  (int)pen4[(size_t)(1 * 4 + b) * N + idx];
        int c23 = (int)pen4[(size_t)(2 * 4 + b) * N + idx] +
                  (int)pen4[(size_t)(3 * 4 + b) * N + idx];
        pw[k] = 1.0f / (float)(c01 + c23);  // exact integer count
        v[k] = 1e10f * pw[k];               // rnd(1e10*pw) == ref's t=0 value
        tab[idx] = make_float4(x[k], y[k], z[k], 0.f);
    }
    if (tid == 0) { slot[0] = 0ull; slot[2] = 0ull; }  // slot[1] zeroed in body 0
    __syncthreads();

    int cur = 0;
    float cx = Pb[0], cy = Pb[1], cz = Pb[2];

    for (int t = 0; t < npoint; ++t) {
        if (tid == 0) {
            out[(size_t)b * npoint + t] = cur;
            slot[(t + 1) % 3] = 0ull;  // safe: last read was before barrier t-1
        }

        // Distance update + f32 chain max (4 chains for ILP).
        float m0 = 0.f, m1 = 0.f, m2 = 0.f, m3 = 0.f;
#pragma unroll
        for (int k = 0; k < FPS_P; ++k) {
            // w=[1,1,2]; fmaf(2,|dz|,s) == s + 2*|dz| bitwise (2*|dz| exact)
            float d = fabsf(x[k] - cx) + fabsf(y[k] - cy);
            d = fmaf(2.0f, fabsf(z[k] - cz), d);
            // v[k] = min over iters of rnd(d*pw) == rnd(min(md,d)*pw) (monotone)
            float nv = fminf(v[k], d * pw[k]);
            v[k] = nv;
            if ((k & 3) == 0)      m0 = fmaxf(m0, nv);
            else if ((k & 3) == 1) m1 = fmaxf(m1, nv);
            else if ((k & 3) == 2) m2 = fmaxf(m2, nv);
            else                   m3 = fmaxf(m3, nv);
        }
        const float tb = fmaxf(fmaxf(m0, m1), fmaxf(m2, m3));  // thread max

        // Descending select-scan: smallest k with v[k] == tb (>=1 match).
        unsigned int ck = 0u;
#pragma unroll
        for (int k = FPS_P - 1; k >= 0; --k)
            ck = (v[k] == tb) ? (unsigned int)k : ck;

        // One u64 key per thread; low word L0-ck -> min global idx on ties.
        unsigned int klo = L0 - ck;
        unsigned int khi = __float_as_uint(tb);  // tb >= 0: bit order == order

        // Wave64 u64 max via DPP: row_shr 1/2/4/8, then row_bcast 15/31.
        DPP_STEP(0x111, 0xF)  // row_shr:1
        DPP_STEP(0x112, 0xF)  // row_shr:2
        DPP_STEP(0x114, 0xF)  // row_shr:4
        DPP_STEP(0x118, 0xF)  // row_shr:8
        DPP_STEP(0x142, 0xA)  // row_bcast:15 -> rows 1,3
        DPP_STEP(0x143, 0xC)  // row_bcast:31 -> rows 2,3

        if (lane == 63) {
            unsigned long long wk = ((unsigned long long)khi << 32) | klo;
            atomicMax(&slot[t % 3], wk);  // ds_max_u64
        }
        __syncthreads();  // single barrier per iteration

        unsigned long long bk = slot[t % 3];
        cur = (N - 1) - (int)((unsigned int)bk & 0xFFFFu);
        float4 c = tab[cur];  // uniform address -> LDS broadcast read
        cx = c.x;
        cy = c.y;
        cz = c.z;
    }
}

extern "C" void kernel_launch(void* const* d_in, const int* in_sizes, int n_in,
                              void* d_out, int out_size, void* d_ws, size_t ws_size,
                              hipStream_t stream) {
    const float* points  = (const float*)d_in[0];
    const int*   npoint  = (const int*)d_in[2];
    int* out = (int*)d_out;

    const int B = 4;
    const int N = in_sizes[0] / (B * 3);  // 8192
    unsigned short* pen4 = (unsigned short*)d_ws;  // 4*B*N ushort = 256 KiB

    dim3 dgrid(N / DENS_BLOCK, B, DENS_SPLIT);
    dfps_density_partial<<<dgrid, DENS_BLOCK, 0, stream>>>(points, pen4, N);

    dfps_fps_kernel<<<B, FPS_THREADS, 0, stream>>>(points, pen4, npoint, out, N);
}

// Round 11
// 1901.671 us; speedup vs baseline: 1.0610x; 1.0610x over previous
//
#include <hip/hip_runtime.h>

// DFPS: density-weighted Manhattan furthest point sampling.
// points:   [B, N, 3] f32   (B=4, N=8192 fixed by the problem)
// features: [B, C, N] f32   (unused)
// npoint:   int scalar (device, d_in[2])
// out:      [B, npoint] int32 indices
//
// FPS structure (R8, best measured: 1854 us dispatch):
//  phase 1: nv = fmin(v, d*pw) per point + f32 chain max (8 VALU/pt),
//           wave DPP f32-max, lane63 ds_max_u32 (f32 bits monotone, v>=0).
//  barrier A; read block max bm.
//  phase 2: waves owning bm (thread-max == bm) scan their 16 values for
//           equality and atomicMin the ORIGINAL index -> first-occurrence
//           tie semantics, bit-exact vs reference (v is bitwise identical
//           to ref's min(md,d)*pw by monotonicity of x->rnd(x*pw)).
//  barrier B; read index slot, fetch coords from LDS float4 table.

#define NPTS 8192
#define DENS_BLOCK 256
#define DENS_SPLIT 8
#define FPS_THREADS 512
#define FPS_P 16   // FPS_THREADS * FPS_P == NPTS

typedef float v2f __attribute__((ext_vector_type(2)));

// ---------------- density ----------------
// j-coords are wave-uniform -> scalar loads, no LDS, no barriers.

__global__ void dfps_density_partial(const float* __restrict__ pts,
                                     unsigned short* __restrict__ pen4, int N) {
#pragma clang fp contract(off)
    const float R2 = (float)(0.4 * 0.4);  // matches JAX scalar promotion
    const int b = blockIdx.y;
    const int z = blockIdx.z;
    const int i = blockIdx.x * blockDim.x + threadIdx.x;
    const float* P = pts + (size_t)b * N * 3;

    const v2f px2 = {P[i * 3 + 0], P[i * 3 + 0]};
    const v2f py2 = {P[i * 3 + 1], P[i * 3 + 1]};
    const v2f pz2 = {P[i * 3 + 2], P[i * 3 + 2]};

    const int j0 = z * (N / DENS_SPLIT);
    const int j1 = j0 + (N / DENS_SPLIT);

    int cnt = 0;
#pragma unroll 4
    for (int j = j0; j < j1; j += 2) {
        v2f qx = {P[3 * j + 0], P[3 * j + 3]};
        v2f qy = {P[3 * j + 1], P[3 * j + 4]};
        v2f qz = {P[3 * j + 2], P[3 * j + 5]};
        v2f dx = px2 - qx;
        v2f dy = py2 - qy;
        v2f dz = pz2 - qz;
        v2f d2 = dx * dx;       // contract(off): numpy mul-then-add rounding
        d2 = d2 + dy * dy;
        d2 = d2 + dz * dz;
        cnt += (d2.x <= R2) ? 1 : 0;
        cnt += (d2.y <= R2) ? 1 : 0;
    }
    pen4[(size_t)(z * 4 + b) * N + i] = (unsigned short)cnt;  // cnt <= 8192
}

// ---------------- FPS ----------------

// f32 max across the wave via DPP (nonneg values; 0-passthrough safe).
#define DPP_MAXF(ctrl, rmask)                                                   \
    {                                                                           \
        float o_ = __uint_as_float((unsigned)__builtin_amdgcn_update_dpp(       \
            0, (int)__float_as_uint(mm), (ctrl), (rmask), 0xF, false));         \
        mm = fmaxf(mm, o_);                                                     \
    }

__global__ void __launch_bounds__(FPS_THREADS, 1)
dfps_fps_kernel(const float* __restrict__ pts,
                const unsigned short* __restrict__ pen4,
                const int* __restrict__ npoint_p,
                int* __restrict__ out, int N) {
#pragma clang fp contract(off)
    const int b = blockIdx.x;
    const int tid = threadIdx.x;
    const int lane = tid & 63;
    const int npoint = *npoint_p;
    const float* Pb = pts + (size_t)b * N * 3;
    const int base = tid * FPS_P;

    // Coordinate table in LDS (float4) -> one b128 winner fetch.
    __shared__ float4 tab[NPTS];                 // 128 KiB
    // Triple-buffered (value, index) slots. Every conflicting access pair is
    // separated by >=1 barrier: atomicMax(v) pre-A, read(v) post-A,
    // atomicMin(i) pre-B, read(i) post-B, re-init 2 iters after last read.
    __shared__ unsigned int vslot[3];
    __shared__ unsigned int islot[3];

    // Per-thread state: coords, penalty, v[k] = running min of rnd(d*pw).
    float x[FPS_P], y[FPS_P], z[FPS_P], pw[FPS_P], v[FPS_P];
#pragma unroll
    for (int k = 0; k < FPS_P; ++k) {
        int idx = base + k;
        x[k] = Pb[idx * 3 + 0];
        y[k] = Pb[idx * 3 + 1];
        z[k] = Pb[idx * 3 + 2];
        int c = 0;
#pragma unroll
        for (int zz = 0; zz < DENS_SPLIT; ++zz)
            c += (int)pen4[(size_t)(zz * 4 + b) * N + idx];
        pw[k] = 1.0f / (float)c;            // exact integer count
        v[k] = 1e10f * pw[k];               // rnd(1e10*pw) == ref's t=0 value
        tab[idx] = make_float4(x[k], y[k], z[k], 0.f);
    }
    if (tid == 0) {
        vslot[0] = 0u; islot[0] = 0xFFFFFFFFu;
        vslot[2] = 0u; islot[2] = 0xFFFFFFFFu;  // slot1 inited in body t=0
    }
    __syncthreads();

    int cur = 0;
    float cx = Pb[0], cy = Pb[1], cz = Pb[2];

    for (int t = 0; t < npoint; ++t) {
        if (tid == 0) {
            out[(size_t)b * npoint + t] = cur;
            vslot[(t + 1) % 3] = 0u;            // next iter's slots; last read
            islot[(t + 1) % 3] = 0xFFFFFFFFu;   // was 2 iters (4 barriers) ago
        }

        // Phase 1: distance update + f32 chain max (4 chains for ILP).
        float m0 = 0.f, m1 = 0.f, m2 = 0.f, m3 = 0.f;
#pragma unroll
        for (int k = 0; k < FPS_P; ++k) {
            // w=[1,1,2]; fmaf(2,|dz|,s) == s + 2*|dz| bitwise (2*|dz| exact)
            float d = fabsf(x[k] - cx) + fabsf(y[k] - cy);
            d = fmaf(2.0f, fabsf(z[k] - cz), d);
            // v[k] = min over iters of rnd(d*pw) == rnd(min(md,d)*pw) (monotone)
            float nv = fminf(v[k], d * pw[k]);
            v[k] = nv;
            if ((k & 3) == 0)      m0 = fmaxf(m0, nv);
            else if ((k & 3) == 1) m1 = fmaxf(m1, nv);
            else if ((k & 3) == 2) m2 = fmaxf(m2, nv);
            else                   m3 = fmaxf(m3, nv);
        }
        const float tb = fmaxf(fmaxf(m0, m1), fmaxf(m2, m3));  // thread max

        // Wave f32 max via DPP: row_shr 1/2/4/8, then row_bcast 15/31.
        float mm = tb;
        DPP_MAXF(0x111, 0xF)  // row_shr:1
        DPP_MAXF(0x112, 0xF)  // row_shr:2
        DPP_MAXF(0x114, 0xF)  // row_shr:4
        DPP_MAXF(0x118, 0xF)  // row_shr:8
        DPP_MAXF(0x142, 0xA)  // row_bcast:15 -> rows 1,3
        DPP_MAXF(0x143, 0xC)  // row_bcast:31 -> rows 2,3
        if (lane == 63)
            atomicMax(&vslot[t % 3], __float_as_uint(mm));  // ds_max_u32

        __syncthreads();  // barrier A: block max ready

        const float bm = __uint_as_float(vslot[t % 3]);

        // Phase 2: only threads whose max equals bm own a candidate; whole
        // waves with no owner skip via exec-mask branch (s_cbranch_execz).
        if (tb == bm) {
            unsigned cand = 0xFFFFFFFFu;
#pragma unroll
            for (int k = 0; k < FPS_P; ++k)
                if (v[k] == bm) cand = min(cand, (unsigned)(base + k));
            atomicMin(&islot[t % 3], cand);  // min ORIGINAL idx -> ref ties
        }

        __syncthreads();  // barrier B: index ready

        cur = (int)islot[t % 3];
        float4 c = tab[cur];  // uniform address -> LDS broadcast read
        cx = c.x;
        cy = c.y;
        cz = c.z;
    }
}

extern "C" void kernel_launch(void* const* d_in, const int* in_sizes, int n_in,
                              void* d_out, int out_size, void* d_ws, size_t ws_size,
                              hipStream_t stream) {
    const float* points  = (const float*)d_in[0];
    const int*   npoint  = (const int*)d_in[2];
    int* out = (int*)d_out;

    const int B = 4;
    const int N = in_sizes[0] / (B * 3);  // 8192
    unsigned short* pen4 = (unsigned short*)d_ws;  // 8*B*N ushort = 512 KiB

    dim3 dgrid(N / DENS_BLOCK, B, DENS_SPLIT);
    dfps_density_partial<<<dgrid, DENS_BLOCK, 0, stream>>>(points, pen4, N);

    dfps_fps_kernel<<<B, FPS_THREADS, 0, stream>>>(points, pen4, npoint, out, N);
}